// Round 10
// baseline (18.778 us; speedup 1.0000x reference)
//
#include <hip/hip_runtime.h>

// Problem constants
#define BB    32
#define N_OPC 512
#define N_MAC 64
#define FF    8
#define HH    128
#define OO    8
#define TM    32      // rows per block
#define ASTRB 136     // activation plane row stride (ushorts), 272B

typedef _Float16 f16x8 __attribute__((ext_vector_type(8)));
typedef _Float16 f16x4 __attribute__((ext_vector_type(4)));
typedef float    f32x4 __attribute__((ext_vector_type(4)));

// ws layout (ushort offsets), fp16 single plane. Frag element:
//   frag[(jt*KS+ks)*64+lane][i] = W[k = ks*32+(lane>>4)*8+i][j = jt*16+(lane&15)], zero-padded.
// Used as the MFMA *A* operand (weights-as-A swapped form).
#define WS_W2  0        // L*16384, L: 0=l0w2 1=l1w2 2=pw2   (8 jt x 4 ks)
#define WS_W3  49152    // L*2048,  L: 0=l0w3 1=l1w3 2=pw3   (1 jt x 4 ks, cols pad 16)
#define WS_W1  55296    // L*4096,  L: 0=l0w1 1=l1w1 2=pw1   (8 jt x 1 ks, K pad 32)
#define WS_FMW 67584    // b*8192: FMW[b] = fm_b(64x8) @ l0w1(8x128), frag (8 jt x 2 ks)
#define PREP_ITEMS (67584 + BB * 8192)   // 329728

__device__ __forceinline__ float elu_f(float x) {
    return x > 0.0f ? x : (__expf(x) - 1.0f);
}

// ---- weight prep: fp32 -> fp16 fragments (single plane) + FMW fusion ----
__global__ void prep_kernel(const float* __restrict__ w20, const float* __restrict__ w21,
                            const float* __restrict__ w22,
                            const float* __restrict__ w30, const float* __restrict__ w31,
                            const float* __restrict__ w32,
                            const float* __restrict__ w10, const float* __restrict__ w11,
                            const float* __restrict__ w12,
                            const float* __restrict__ fmab,
                            ushort* __restrict__ ws)
{
    const int gid = blockIdx.x * 256 + threadIdx.x;
    if (gid < 3 * 16384) {                       // W2: 128x128
        const int layer = gid >> 14, idx = gid & 16383;
        const float* w = layer == 0 ? w20 : layer == 1 ? w21 : w22;
        const int k = idx >> 7, j = idx & 127;
        const float x = w[idx];
        const int ks = k >> 5, kk = k & 31, jt = j >> 4, jj = j & 15;
        const int lane = ((kk >> 3) << 4) | jj, i = kk & 7;
        const int off = (((jt * 4 + ks) * 64 + lane) << 3) + i;
        const _Float16 h = (_Float16)x;
        ws[WS_W2 + layer * 16384 + off] = __builtin_bit_cast(ushort, h);
    } else if (gid < 3 * 16384 + 3 * 2048) {     // W3: 128x8 padded to 16 cols
        const int g2 = gid - 3 * 16384;
        const int layer = g2 >> 11, idx = g2 & 2047;
        const float* w = layer == 0 ? w30 : layer == 1 ? w31 : w32;
        const int i = idx & 7, lane = (idx >> 3) & 63, ks = idx >> 9;
        const int k = ks * 32 + (lane >> 4) * 8 + i, j = lane & 15;
        const float x = (j < OO) ? w[k * OO + j] : 0.0f;
        const _Float16 h = (_Float16)x;
        ws[WS_W3 + layer * 2048 + idx] = __builtin_bit_cast(ushort, h);
    } else if (gid < 67584) {                    // W1: Kx128, K padded to 32
        const int g1 = gid - (3 * 16384 + 3 * 2048);
        const int layer = g1 >> 12, idx = g1 & 4095;
        const float* w = layer == 0 ? w10 : layer == 1 ? w11 : w12;
        const int i = idx & 7, lane = (idx >> 3) & 63, jt = idx >> 9;
        const int k = (lane >> 4) * 8 + i, j = jt * 16 + (lane & 15);
        const int Kr = (layer == 2) ? 16 : 8;
        const float x = (k < Kr) ? w[k * HH + j] : 0.0f;
        const _Float16 h = (_Float16)x;
        ws[WS_W1 + layer * 4096 + idx] = __builtin_bit_cast(ushort, h);
    } else {                                     // FMW[b] = fm_b @ l0w1, K=64 frags
        const int g = gid - WS_FMW;
        const int bb = g >> 13, idx = g & 8191;
        const int i = idx & 7, lane = (idx >> 3) & 63, fk = idx >> 9;
        const int ks = fk & 1, jt = fk >> 1;
        const int k = ks * 32 + (lane >> 4) * 8 + i;    // machine index 0..63
        const int j = jt * 16 + (lane & 15);            // output feature 0..127
        const float* fmr = fmab + bb * (N_MAC * FF) + k * FF;
        float x = 0.0f;
        #pragma unroll
        for (int f = 0; f < FF; ++f) x = fmaf(fmr[f], w10[f * HH + j], x);
        const _Float16 h = (_Float16)x;
        ws[WS_FMW + g] = __builtin_bit_cast(ushort, h);
    }
}

// epilogue: acc (4 consecutive output features) + bias -> elu -> fp16 -> 1x ds_write_b64
__device__ __forceinline__ void epi_store(f32x4 a, const float* __restrict__ bias, int jb,
                                          ushort* __restrict__ dst, int off)
{
    const float4 bb = *(const float4*)(bias + jb);
    f16x4 v;
    v[0] = (_Float16)elu_f(a[0] + bb.x);
    v[1] = (_Float16)elu_f(a[1] + bb.y);
    v[2] = (_Float16)elu_f(a[2] + bb.z);
    v[3] = (_Float16)elu_f(a[3] + bb.w);
    *(f16x4*)(dst + off) = v;
}

__global__ __launch_bounds__(512, 4) void mlps_kernel(
    const int*   __restrict__ adj,
    const float* __restrict__ fop,
    const float* __restrict__ l0b1, const float* __restrict__ l0b2, const float* __restrict__ l0b3,
    const float* __restrict__ l1b1, const float* __restrict__ l1b2, const float* __restrict__ l1b3,
    const float* __restrict__ pb1,  const float* __restrict__ pb2,  const float* __restrict__ pb3,
    const ushort* __restrict__ wsf,
    float* __restrict__ out)
{
    __shared__ __align__(16) ushort hbuf[2][TM * ASTRB];   // [br], single fp16 plane
    __shared__ __align__(16) ushort gbuf[2][TM * ASTRB];
    __shared__ __align__(16) ushort catF[TM * 16];

    const int tid  = threadIdx.x;
    const int wv   = tid >> 6;
    const int lane = tid & 63;
    const int lrow = lane & 15;       // activation row within 16-row tile
    const int lk   = lane >> 4;       // k-octet / output-feature quad
    const int row0 = blockIdx.x * TM;
    const int b    = row0 / N_OPC;
    const int br   = wv >> 2, jt0 = (wv & 3) * 2;

    // ======== P1: input layers, fully from global (no staging, no agg phase) ========
    f32x4 acc1[2][2] = {};
    if (br == 0) {
        // branch 0: emb0_in = elu(adj @ FMW + b1), FMW = fm @ l0w1 (prep-fused), K=64
        const f16x8* FMWF = (const f16x8*)(wsf + WS_FMW + b * 8192);
        f16x8 wa[2][2];
        #pragma unroll
        for (int jtl = 0; jtl < 2; ++jtl)
            #pragma unroll
            for (int ks = 0; ks < 2; ++ks)
                wa[jtl][ks] = FMWF[((jt0 + jtl) * 2 + ks) * 64 + lane];
        f16x8 xb[2][2];
        #pragma unroll
        for (int rt = 0; rt < 2; ++rt)
            #pragma unroll
            for (int ks = 0; ks < 2; ++ks) {
                const int* ap = adj + (row0 + rt * 16 + lrow) * N_MAC + ks * 32 + lk * 8;
                const int4 a0 = *(const int4*)ap;
                const int4 a1 = *(const int4*)(ap + 4);
                f16x8 v;
                v[0] = (_Float16)a0.x; v[1] = (_Float16)a0.y;
                v[2] = (_Float16)a0.z; v[3] = (_Float16)a0.w;
                v[4] = (_Float16)a1.x; v[5] = (_Float16)a1.y;
                v[6] = (_Float16)a1.z; v[7] = (_Float16)a1.w;
                xb[rt][ks] = v;
            }
        #pragma unroll
        for (int jtl = 0; jtl < 2; ++jtl)
            #pragma unroll
            for (int rt = 0; rt < 2; ++rt)
                #pragma unroll
                for (int ks = 0; ks < 2; ++ks)
                    acc1[jtl][rt] = __builtin_amdgcn_mfma_f32_16x16x32_f16(wa[jtl][ks], xb[rt][ks], acc1[jtl][rt], 0, 0, 0);
    } else {
        // branch 1: emb1_in = elu(fop @ l1w1 + b1), K=8 pad 32, fop direct from global
        const f16x8* WF = (const f16x8*)(wsf + WS_W1 + 4096);
        const f16x8 w1a = WF[jt0 * 64 + lane];
        const f16x8 w1b = WF[(jt0 + 1) * 64 + lane];
        f16x8 X[2] = {};
        if (lk == 0) {
            #pragma unroll
            for (int rt = 0; rt < 2; ++rt) {
                const float* src = fop + (row0 + rt * 16 + lrow) * FF;
                const float4 f0 = *(const float4*)src;
                const float4 f1 = *(const float4*)(src + 4);
                f16x8 v;
                v[0] = (_Float16)f0.x; v[1] = (_Float16)f0.y;
                v[2] = (_Float16)f0.z; v[3] = (_Float16)f0.w;
                v[4] = (_Float16)f1.x; v[5] = (_Float16)f1.y;
                v[6] = (_Float16)f1.z; v[7] = (_Float16)f1.w;
                X[rt] = v;
            }
        }
        #pragma unroll
        for (int rt = 0; rt < 2; ++rt) {
            acc1[0][rt] = __builtin_amdgcn_mfma_f32_16x16x32_f16(w1a, X[rt], acc1[0][rt], 0, 0, 0);
            acc1[1][rt] = __builtin_amdgcn_mfma_f32_16x16x32_f16(w1b, X[rt], acc1[1][rt], 0, 0, 0);
        }
    }
    // preload P2 heavy frags (fly during epilogue + barrier)
    f16x8 wf2[2][4];
    {
        const f16x8* W2F = (const f16x8*)(wsf + WS_W2 + br * 16384);
        #pragma unroll
        for (int jtl = 0; jtl < 2; ++jtl)
            #pragma unroll
            for (int ks = 0; ks < 4; ++ks)
                wf2[jtl][ks] = W2F[((jt0 + jtl) * 4 + ks) * 64 + lane];
    }
    {
        const float* b1 = br ? l1b1 : l0b1;
        #pragma unroll
        for (int jtl = 0; jtl < 2; ++jtl) {
            const int jb = (jt0 + jtl) * 16 + lk * 4;
            #pragma unroll
            for (int rt = 0; rt < 2; ++rt)
                epi_store(acc1[jtl][rt], b1, jb, hbuf[br], (rt * 16 + lrow) * ASTRB + jb);
        }
    }
    __syncthreads();

    // ======== P2: heavy layers (128x128), frags preloaded ========
    // preload P3 frags
    f16x8 wf3[4];
    if (wv < 4) {
        const f16x8* WF3 = (const f16x8*)(wsf + WS_W3 + (wv >> 1) * 2048);
        #pragma unroll
        for (int ks = 0; ks < 4; ++ks) wf3[ks] = WF3[ks * 64 + lane];
    }
    {
        const ushort* aF = hbuf[br];
        f32x4 acc[2][2] = {};
        #pragma unroll
        for (int ks = 0; ks < 4; ++ks) {
            f16x8 x[2];
            #pragma unroll
            for (int rt = 0; rt < 2; ++rt)
                x[rt] = *(const f16x8*)(aF + (rt * 16 + lrow) * ASTRB + ks * 32 + lk * 8);
            #pragma unroll
            for (int jtl = 0; jtl < 2; ++jtl)
                #pragma unroll
                for (int rt = 0; rt < 2; ++rt)
                    acc[jtl][rt] = __builtin_amdgcn_mfma_f32_16x16x32_f16(wf2[jtl][ks], x[rt], acc[jtl][rt], 0, 0, 0);
        }
        const float* b2 = br ? l1b2 : l0b2;
        #pragma unroll
        for (int jtl = 0; jtl < 2; ++jtl) {
            const int jb = (jt0 + jtl) * 16 + lk * 4;
            #pragma unroll
            for (int rt = 0; rt < 2; ++rt)
                epi_store(acc[jtl][rt], b2, jb, gbuf[br], (rt * 16 + lrow) * ASTRB + jb);
        }
    }
    __syncthreads();

    // ======== P3: branch output layers (128 -> 8 pad 16), waves 0-3 ========
    // preload P4 frag (all waves)
    f16x8 wf4;
    {
        const f16x8* WF = (const f16x8*)(wsf + WS_W1 + 2 * 4096);
        wf4 = WF[wv * 64 + lane];
    }
    if (wv < 4) {
        const int br3 = wv >> 1, rt = wv & 1;
        const ushort* aF = gbuf[br3];
        f32x4 acc = {};
        #pragma unroll
        for (int ks = 0; ks < 4; ++ks) {
            const f16x8 x = *(const f16x8*)(aF + (rt * 16 + lrow) * ASTRB + ks * 32 + lk * 8);
            acc = __builtin_amdgcn_mfma_f32_16x16x32_f16(wf3[ks], x, acc, 0, 0, 0);
        }
        if (lk < 2) {
            const float* b3 = br3 ? l1b3 : l0b3;
            epi_store(acc, b3, lk * 4, catF, (rt * 16 + lrow) * 16 + br3 * OO + lk * 4);
        }
    }
    __syncthreads();

    // ======== P4: proj input layer (K=16 pad 32) ========
    // preload P5 frags
    f16x8 wf5[4];
    {
        const f16x8* WF = (const f16x8*)(wsf + WS_W2 + 2 * 16384);
        #pragma unroll
        for (int ks = 0; ks < 4; ++ks) wf5[ks] = WF[(wv * 4 + ks) * 64 + lane];
    }
    {
        f16x8 X[2] = {};
        if (lk < 2) {
            #pragma unroll
            for (int rt = 0; rt < 2; ++rt)
                X[rt] = *(const f16x8*)(catF + (rt * 16 + lrow) * 16 + lk * 8);
        }
        f32x4 acc[2] = {};
        #pragma unroll
        for (int rt = 0; rt < 2; ++rt)
            acc[rt] = __builtin_amdgcn_mfma_f32_16x16x32_f16(wf4, X[rt], acc[rt], 0, 0, 0);
        const int jb = wv * 16 + lk * 4;
        #pragma unroll
        for (int rt = 0; rt < 2; ++rt)
            epi_store(acc[rt], pb1, jb, hbuf[0], (rt * 16 + lrow) * ASTRB + jb);
    }
    __syncthreads();

    // ======== P5: proj heavy layer ========
    // preload P6 frags
    f16x8 wf6[4];
    if (wv < 2) {
        const f16x8* WF = (const f16x8*)(wsf + WS_W3 + 2 * 2048);
        #pragma unroll
        for (int ks = 0; ks < 4; ++ks) wf6[ks] = WF[ks * 64 + lane];
    }
    {
        const ushort* aF = hbuf[0];
        f32x4 acc[2] = {};
        #pragma unroll
        for (int ks = 0; ks < 4; ++ks) {
            #pragma unroll
            for (int rt = 0; rt < 2; ++rt) {
                const f16x8 x = *(const f16x8*)(aF + (rt * 16 + lrow) * ASTRB + ks * 32 + lk * 8);
                acc[rt] = __builtin_amdgcn_mfma_f32_16x16x32_f16(wf5[ks], x, acc[rt], 0, 0, 0);
            }
        }
        const int jb = wv * 16 + lk * 4;
        #pragma unroll
        for (int rt = 0; rt < 2; ++rt)
            epi_store(acc[rt], pb2, jb, gbuf[0], (rt * 16 + lrow) * ASTRB + jb);
    }
    __syncthreads();

    // ======== P6: proj output layer (128 -> 8), waves 0,1, dwordx4 store ========
    if (wv < 2) {
        const int rt = wv;
        const ushort* aF = gbuf[0];
        f32x4 acc = {};
        #pragma unroll
        for (int ks = 0; ks < 4; ++ks) {
            const f16x8 x = *(const f16x8*)(aF + (rt * 16 + lrow) * ASTRB + ks * 32 + lk * 8);
            acc = __builtin_amdgcn_mfma_f32_16x16x32_f16(wf6[ks], x, acc, 0, 0, 0);
        }
        if (lk < 2) {
            const float4 bb = *(const float4*)(pb3 + lk * 4);
            float4 o;
            o.x = acc[0] + bb.x; o.y = acc[1] + bb.y;
            o.z = acc[2] + bb.z; o.w = acc[3] + bb.w;
            *(float4*)(out + (row0 + rt * 16 + lrow) * OO + lk * 4) = o;
        }
    }
}

extern "C" void kernel_launch(void* const* d_in, const int* in_sizes, int n_in,
                              void* d_out, int out_size, void* d_ws, size_t ws_size,
                              hipStream_t stream) {
    (void)in_sizes; (void)n_in; (void)out_size; (void)ws_size;
    const int*   adj  = (const int*)  d_in[0];
    const float* fop  = (const float*)d_in[1];
    const float* fmab = (const float*)d_in[2];
    const float* l0w1 = (const float*)d_in[3];
    const float* l0b1 = (const float*)d_in[4];
    const float* l0w2 = (const float*)d_in[5];
    const float* l0b2 = (const float*)d_in[6];
    const float* l0w3 = (const float*)d_in[7];
    const float* l0b3 = (const float*)d_in[8];
    const float* l1w1 = (const float*)d_in[9];
    const float* l1b1 = (const float*)d_in[10];
    const float* l1w2 = (const float*)d_in[11];
    const float* l1b2 = (const float*)d_in[12];
    const float* l1w3 = (const float*)d_in[13];
    const float* l1b3 = (const float*)d_in[14];
    const float* pw1  = (const float*)d_in[15];
    const float* pb1  = (const float*)d_in[16];
    const float* pw2  = (const float*)d_in[17];
    const float* pb2  = (const float*)d_in[18];
    const float* pw3  = (const float*)d_in[19];
    const float* pb3  = (const float*)d_in[20];
    float* out = (float*)d_out;
    ushort* wsf = (ushort*)d_ws;

    const int prep_blocks = PREP_ITEMS / 256;   // 1288
    prep_kernel<<<dim3(prep_blocks), dim3(256), 0, stream>>>(
        l0w2, l1w2, pw2, l0w3, l1w3, pw3, l0w1, l1w1, pw1, fmab, wsf);

    const int grid = (BB * N_OPC) / TM;   // 512
    mlps_kernel<<<dim3(grid), dim3(512), 0, stream>>>(
        adj, fop,
        l0b1, l0b2, l0b3,
        l1b1, l1b2, l1b3,
        pb1, pb2, pb3,
        wsf, out);
}

// Round 11
// 17.768 us; speedup vs baseline: 1.0569x; 1.0569x over previous
//
#include <hip/hip_runtime.h>

// Problem constants
#define BB    32
#define N_OPC 512
#define N_MAC 64
#define FF    8
#define HH    128
#define OO    8
#define TM    32      // rows per block
#define ASTRB 136     // activation plane row stride (ushorts), 272B

typedef _Float16 f16x8 __attribute__((ext_vector_type(8)));
typedef _Float16 f16x4 __attribute__((ext_vector_type(4)));
typedef float    f32x4 __attribute__((ext_vector_type(4)));

__device__ __forceinline__ float elu_f(float x) {
    return x > 0.0f ? x : (__expf(x) - 1.0f);
}
__device__ __forceinline__ void store_f16(float v, ushort* dst, int off) {
    const _Float16 h = (_Float16)v;
    dst[off] = __builtin_bit_cast(ushort, h);
}
// gather one MFMA A-fragment (weights-as-A swapped form) straight from fp32 W:
//   elem i = W[kbase+i][j], row-major leading dim ld. Lanes cover j=16 consecutive
//   cols (64B segments) x 4 k-octets -> dense segments, L1/L2-hot.
__device__ __forceinline__ f16x8 gather8(const float* __restrict__ w, int kbase, int j, int ld) {
    f16x8 v;
    #pragma unroll
    for (int i = 0; i < 8; ++i)
        v[i] = (_Float16)w[(kbase + i) * ld + j];
    return v;
}

// epilogue: acc (4 consecutive output features) + bias -> elu -> fp16 -> 1x ds_write_b64
__device__ __forceinline__ void epi_store(f32x4 a, const float* __restrict__ bias, int jb,
                                          ushort* __restrict__ dst, int off)
{
    const float4 bb = *(const float4*)(bias + jb);
    f16x4 v;
    v[0] = (_Float16)elu_f(a[0] + bb.x);
    v[1] = (_Float16)elu_f(a[1] + bb.y);
    v[2] = (_Float16)elu_f(a[2] + bb.z);
    v[3] = (_Float16)elu_f(a[3] + bb.w);
    *(f16x4*)(dst + off) = v;
}

__global__ __launch_bounds__(512, 4) void mlps_kernel(
    const int*   __restrict__ adj,
    const float* __restrict__ fop,
    const float* __restrict__ fmab,
    const float* __restrict__ l0w1, const float* __restrict__ l0b1,
    const float* __restrict__ l0w2, const float* __restrict__ l0b2,
    const float* __restrict__ l0w3, const float* __restrict__ l0b3,
    const float* __restrict__ l1w1, const float* __restrict__ l1b1,
    const float* __restrict__ l1w2, const float* __restrict__ l1b2,
    const float* __restrict__ l1w3, const float* __restrict__ l1b3,
    const float* __restrict__ pw1,  const float* __restrict__ pb1,
    const float* __restrict__ pw2,  const float* __restrict__ pb2,
    const float* __restrict__ pw3,  const float* __restrict__ pb3,
    float* __restrict__ out)
{
    __shared__ __align__(16) ushort hbuf[2][TM * ASTRB];   // [br], single fp16 plane
    __shared__ __align__(16) ushort gbuf[2][TM * ASTRB];
    __shared__ float fmS[N_MAC * FF];
    __shared__ __align__(16) ushort xinF[TM * FF];
    __shared__ __align__(16) ushort xopF[TM * FF];
    __shared__ __align__(16) ushort catF[TM * 16];

    const int tid  = threadIdx.x;
    const int wv   = tid >> 6;
    const int lane = tid & 63;
    const int lrow = lane & 15;       // activation row within 16-row tile / weight col
    const int lk   = lane >> 4;       // k-octet / output-feature quad
    const int row0 = blockIdx.x * TM;
    const int b    = row0 / N_OPC;
    const int br   = wv >> 2, jt0 = (wv & 3) * 2;

    // ---- early gathers: P1 input-layer frags (K=8 -> only lk==0 rows) + P2 heavy frags
    const float* w1p = br ? l1w1 : l0w1;
    f16x8 w1f[2] = {};
    if (lk == 0) {
        w1f[0] = gather8(w1p, 0, jt0 * 16 + lrow, HH);
        w1f[1] = gather8(w1p, 0, (jt0 + 1) * 16 + lrow, HH);
    }
    const float* w2p = br ? l1w2 : l0w2;
    f16x8 wf2[2][4];
    #pragma unroll
    for (int jtl = 0; jtl < 2; ++jtl)
        #pragma unroll
        for (int ks = 0; ks < 4; ++ks)
            wf2[jtl][ks] = gather8(w2p, ks * 32 + lk * 8, (jt0 + jtl) * 16 + lrow, HH);

    // ---- stage: machine feats (fp32), op feats (fp16)
    fmS[tid] = fmab[b * N_MAC * FF + tid];
    if (tid < TM * FF)
        store_f16(fop[row0 * FF + tid], xopF, tid);
    __syncthreads();

    // ---- aggregation: xin[r][f] = sum_m adj[r][m] * fm[m][f]
    if (tid < TM * FF) {
        const int r = tid >> 3, f = tid & 7;
        const int* arow = adj + (row0 + r) * N_MAC;
        float a = 0.0f;
        #pragma unroll
        for (int m4 = 0; m4 < N_MAC; m4 += 4) {
            const int4 av = *(const int4*)(arow + m4);
            a = fmaf((float)av.x, fmS[(m4 + 0) * FF + f], a);
            a = fmaf((float)av.y, fmS[(m4 + 1) * FF + f], a);
            a = fmaf((float)av.z, fmS[(m4 + 2) * FF + f], a);
            a = fmaf((float)av.w, fmS[(m4 + 3) * FF + f], a);
        }
        store_f16(a, xinF, tid);
    }
    __syncthreads();

    // ---- P1: input layers (K=8 pad 32): waves 0-3 br0, 4-7 br1; 2 jtiles x 2 rowtiles
    {
        const ushort* xF = br ? xopF : xinF;
        const float* b1 = br ? l1b1 : l0b1;
        f16x8 X[2] = {};
        if (lk == 0) {
            #pragma unroll
            for (int rt = 0; rt < 2; ++rt)
                X[rt] = *(const f16x8*)(xF + (rt * 16 + lrow) * 8);
        }
        f32x4 acc[2][2] = {};
        #pragma unroll
        for (int jtl = 0; jtl < 2; ++jtl)
            #pragma unroll
            for (int rt = 0; rt < 2; ++rt)
                acc[jtl][rt] = __builtin_amdgcn_mfma_f32_16x16x32_f16(w1f[jtl], X[rt], acc[jtl][rt], 0, 0, 0);
        #pragma unroll
        for (int jtl = 0; jtl < 2; ++jtl) {
            const int jb = (jt0 + jtl) * 16 + lk * 4;
            #pragma unroll
            for (int rt = 0; rt < 2; ++rt)
                epi_store(acc[jtl][rt], b1, jb, hbuf[br], (rt * 16 + lrow) * ASTRB + jb);
        }
    }
    __syncthreads();

    // ---- gather P3 frags (W3: 128x8, cols lrow<8 valid)
    f16x8 wf3[4] = {};
    if (wv < 4 && lrow < OO) {
        const float* w3p = (wv >> 1) ? l1w3 : l0w3;
        #pragma unroll
        for (int ks = 0; ks < 4; ++ks)
            wf3[ks] = gather8(w3p, ks * 32 + lk * 8, lrow, OO);
    }
    // ---- P2: heavy layers (128x128), frags preloaded
    {
        const ushort* aF = hbuf[br];
        f32x4 acc[2][2] = {};
        #pragma unroll
        for (int ks = 0; ks < 4; ++ks) {
            f16x8 x[2];
            #pragma unroll
            for (int rt = 0; rt < 2; ++rt)
                x[rt] = *(const f16x8*)(aF + (rt * 16 + lrow) * ASTRB + ks * 32 + lk * 8);
            #pragma unroll
            for (int jtl = 0; jtl < 2; ++jtl)
                #pragma unroll
                for (int rt = 0; rt < 2; ++rt)
                    acc[jtl][rt] = __builtin_amdgcn_mfma_f32_16x16x32_f16(wf2[jtl][ks], x[rt], acc[jtl][rt], 0, 0, 0);
        }
        const float* b2 = br ? l1b2 : l0b2;
        #pragma unroll
        for (int jtl = 0; jtl < 2; ++jtl) {
            const int jb = (jt0 + jtl) * 16 + lk * 4;
            #pragma unroll
            for (int rt = 0; rt < 2; ++rt)
                epi_store(acc[jtl][rt], b2, jb, gbuf[br], (rt * 16 + lrow) * ASTRB + jb);
        }
    }
    __syncthreads();

    // ---- gather P4 frag (pw1, K=16 -> lk<2 rows)
    f16x8 wf4 = {};
    if (lk < 2)
        wf4 = gather8(pw1, lk * 8, wv * 16 + lrow, HH);
    // ---- P3: branch output layers (128 -> 8 pad 16): waves 0-3
    if (wv < 4) {
        const int br3 = wv >> 1, rt = wv & 1;
        const ushort* aF = gbuf[br3];
        f32x4 acc = {};
        #pragma unroll
        for (int ks = 0; ks < 4; ++ks) {
            const f16x8 x = *(const f16x8*)(aF + (rt * 16 + lrow) * ASTRB + ks * 32 + lk * 8);
            acc = __builtin_amdgcn_mfma_f32_16x16x32_f16(wf3[ks], x, acc, 0, 0, 0);
        }
        if (lk < 2) {
            const float* b3 = br3 ? l1b3 : l0b3;
            epi_store(acc, b3, lk * 4, catF, (rt * 16 + lrow) * 16 + br3 * OO + lk * 4);
        }
    }
    __syncthreads();

    // ---- gather P5 frags (pw2)
    f16x8 wf5[4];
    #pragma unroll
    for (int ks = 0; ks < 4; ++ks)
        wf5[ks] = gather8(pw2, ks * 32 + lk * 8, wv * 16 + lrow, HH);
    // ---- P4: proj input layer (K=16 pad 32): wave wv -> jtile wv, 2 rowtiles
    {
        f16x8 X[2] = {};
        if (lk < 2) {
            #pragma unroll
            for (int rt = 0; rt < 2; ++rt)
                X[rt] = *(const f16x8*)(catF + (rt * 16 + lrow) * 16 + lk * 8);
        }
        f32x4 acc[2] = {};
        #pragma unroll
        for (int rt = 0; rt < 2; ++rt)
            acc[rt] = __builtin_amdgcn_mfma_f32_16x16x32_f16(wf4, X[rt], acc[rt], 0, 0, 0);
        const int jb = wv * 16 + lk * 4;
        #pragma unroll
        for (int rt = 0; rt < 2; ++rt)
            epi_store(acc[rt], pb1, jb, hbuf[0], (rt * 16 + lrow) * ASTRB + jb);
    }
    __syncthreads();

    // ---- gather P6 frags (pw3)
    f16x8 wf6[4] = {};
    if (wv < 2 && lrow < OO) {
        #pragma unroll
        for (int ks = 0; ks < 4; ++ks)
            wf6[ks] = gather8(pw3, ks * 32 + lk * 8, lrow, OO);
    }
    // ---- P5: proj heavy layer (128x128): wave wv -> jtile wv, 2 rowtiles
    {
        const ushort* aF = hbuf[0];
        f32x4 acc[2] = {};
        #pragma unroll
        for (int ks = 0; ks < 4; ++ks) {
            #pragma unroll
            for (int rt = 0; rt < 2; ++rt) {
                const f16x8 x = *(const f16x8*)(aF + (rt * 16 + lrow) * ASTRB + ks * 32 + lk * 8);
                acc[rt] = __builtin_amdgcn_mfma_f32_16x16x32_f16(wf5[ks], x, acc[rt], 0, 0, 0);
            }
        }
        const int jb = wv * 16 + lk * 4;
        #pragma unroll
        for (int rt = 0; rt < 2; ++rt)
            epi_store(acc[rt], pb2, jb, gbuf[0], (rt * 16 + lrow) * ASTRB + jb);
    }
    __syncthreads();

    // ---- P6: proj output layer (128 -> 8): waves 0,1 -> rowtiles, dwordx4 store
    if (wv < 2) {
        const int rt = wv;
        const ushort* aF = gbuf[0];
        f32x4 acc = {};
        #pragma unroll
        for (int ks = 0; ks < 4; ++ks) {
            const f16x8 x = *(const f16x8*)(aF + (rt * 16 + lrow) * ASTRB + ks * 32 + lk * 8);
            acc = __builtin_amdgcn_mfma_f32_16x16x32_f16(wf6[ks], x, acc, 0, 0, 0);
        }
        if (lk < 2) {
            const float4 bb = *(const float4*)(pb3 + lk * 4);
            float4 o;
            o.x = acc[0] + bb.x; o.y = acc[1] + bb.y;
            o.z = acc[2] + bb.z; o.w = acc[3] + bb.w;
            *(float4*)(out + (row0 + rt * 16 + lrow) * OO + lk * 4) = o;
        }
    }
}

extern "C" void kernel_launch(void* const* d_in, const int* in_sizes, int n_in,
                              void* d_out, int out_size, void* d_ws, size_t ws_size,
                              hipStream_t stream) {
    (void)in_sizes; (void)n_in; (void)out_size; (void)d_ws; (void)ws_size;
    const int*   adj  = (const int*)  d_in[0];
    const float* fop  = (const float*)d_in[1];
    const float* fmab = (const float*)d_in[2];
    const float* l0w1 = (const float*)d_in[3];
    const float* l0b1 = (const float*)d_in[4];
    const float* l0w2 = (const float*)d_in[5];
    const float* l0b2 = (const float*)d_in[6];
    const float* l0w3 = (const float*)d_in[7];
    const float* l0b3 = (const float*)d_in[8];
    const float* l1w1 = (const float*)d_in[9];
    const float* l1b1 = (const float*)d_in[10];
    const float* l1w2 = (const float*)d_in[11];
    const float* l1b2 = (const float*)d_in[12];
    const float* l1w3 = (const float*)d_in[13];
    const float* l1b3 = (const float*)d_in[14];
    const float* pw1  = (const float*)d_in[15];
    const float* pb1  = (const float*)d_in[16];
    const float* pw2  = (const float*)d_in[17];
    const float* pb2  = (const float*)d_in[18];
    const float* pw3  = (const float*)d_in[19];
    const float* pb3  = (const float*)d_in[20];
    float* out = (float*)d_out;

    const int grid = (BB * N_OPC) / TM;   // 512
    mlps_kernel<<<dim3(grid), dim3(512), 0, stream>>>(
        adj, fop, fmab,
        l0w1, l0b1, l0w2, l0b2, l0w3, l0b3,
        l1w1, l1b1, l1w2, l1b2, l1w3, l1b3,
        pw1, pb1, pw2, pb2, pw3, pb3,
        out);
}